// Round 1
// baseline (1458.791 us; speedup 1.0000x reference)
//
#include <hip/hip_runtime.h>
#include <hip/hip_bf16.h>
#include <math.h>

// ---------------------------------------------------------------------------
// FederatedPPOAgent: 3x GCNConv (N=100k, E=3.2M, D=128) + actor/critic MLPs.
//
// Plan:
//   deg/dinv  : count in-degree (+1 self loop), dinv = rsqrt(deg)
//   CSR build : row_ptr via block scan, col[] via atomic slot fill (by dst)
//   per layer : hprime = (X @ W) * dinv[row]    (fp32 tile GEMM, x-tile in LDS)
//               h_out  = act((sum_{e->d} hprime[src] + hprime[d]) * dinv[d] + b)
//                        (wave-per-node gather-sum, no atomics)
//   heads     : per-64-node tile, whole actor+critic chain in LDS, softmax,
//               coalesced [N,9] store.
// ---------------------------------------------------------------------------

#define WS_ALIGN(x) (((x) + 255) & ~(size_t)255)

// ---------------- degree / CSR build ----------------

__global__ void zero_int_k(int* p, int n) {
    int i = blockIdx.x * 256 + threadIdx.x;
    if (i < n) p[i] = 0;
}

__global__ void count_k(const int* __restrict__ dst, int* __restrict__ cnt, int E) {
    int e = blockIdx.x * 256 + threadIdx.x;
    if (e < E) atomicAdd(&cnt[dst[e]], 1);
}

__global__ void dinv_k(const int* __restrict__ cnt, float* __restrict__ dinv, int n) {
    int i = blockIdx.x * 256 + threadIdx.x;
    if (i < n) dinv[i] = rsqrtf((float)cnt[i] + 1.0f);   // +1: self loop
}

__global__ void chunk_sum_k(const int* __restrict__ cnt, int* __restrict__ bsum, int n) {
    __shared__ int sd[256];
    int t = threadIdx.x;
    int i = blockIdx.x * 256 + t;
    sd[t] = (i < n) ? cnt[i] : 0;
    __syncthreads();
    for (int d = 128; d > 0; d >>= 1) {
        if (t < d) sd[t] += sd[t + d];
        __syncthreads();
    }
    if (t == 0) bsum[blockIdx.x] = sd[0];
}

// single block, 512 threads; nb <= 512
__global__ void scan_mid_k(const int* __restrict__ bsum, int* __restrict__ boff,
                           int nb, int* __restrict__ rowptr, int N) {
    __shared__ int s[512];
    int t = threadIdx.x;
    s[t] = (t < nb) ? bsum[t] : 0;
    __syncthreads();
    if (t == 0) {
        int run = 0;
        for (int i = 0; i < nb; i++) { int v = s[i]; s[i] = run; run += v; }
        rowptr[N] = run;  // total edges
    }
    __syncthreads();
    if (t < nb) boff[t] = s[t];
}

__global__ void scan_final_k(const int* __restrict__ cnt, const int* __restrict__ boff,
                             int* __restrict__ rowptr, int* __restrict__ cursor, int n) {
    __shared__ int s[256];
    int t = threadIdx.x;
    int i = blockIdx.x * 256 + t;
    int v = (i < n) ? cnt[i] : 0;
    s[t] = v;
    __syncthreads();
    // Hillis-Steele inclusive scan
    for (int d = 1; d < 256; d <<= 1) {
        int x = (t >= d) ? s[t - d] : 0;
        __syncthreads();
        s[t] += x;
        __syncthreads();
    }
    if (i < n) {
        int ex = s[t] - v + boff[blockIdx.x];  // exclusive
        rowptr[i] = ex;
        cursor[i] = ex;
    }
}

__global__ void fill_csr_k(const int* __restrict__ src, const int* __restrict__ dst,
                           int* __restrict__ cursor, int* __restrict__ col, int E) {
    int e = blockIdx.x * 256 + threadIdx.x;
    if (e < E) {
        int slot = atomicAdd(&cursor[dst[e]], 1);
        col[slot] = src[e];
    }
}

// ---------------- GEMM: Y[r,:] = (X[r,:] @ W) * dinv[r] ----------------
// X:[N,128], W:[128,OUT], OUT in {128,64}. 64-row tile per 256-thread block.

template <int OUT>
__global__ __launch_bounds__(256) void gemm_scaled_k(
    const float* __restrict__ X, const float* __restrict__ W,
    const float* __restrict__ dinv, float* __restrict__ Y, int N) {
    constexpr int TR = 64;
    __shared__ __align__(16) float xs[TR][132];   // pad: 132 % 32 banks -> free 2-way
    int t = threadIdx.x;
    int rowBase = blockIdx.x * TR;

    // stage x tile (64 x 128) with float4 loads
    for (int i = t; i < TR * 32; i += 256) {
        int r = i >> 5, q = i & 31;
        int gr = rowBase + r;
        float4 v = make_float4(0.f, 0.f, 0.f, 0.f);
        if (gr < N) v = ((const float4*)(X + (size_t)gr * 128))[q];
        *(float4*)&xs[r][q * 4] = v;
    }
    __syncthreads();

    constexpr int CG = OUT / 8;             // col groups of 8
    constexpr int RPT = (TR * CG) / 256;    // rows per thread: 4 (OUT=128), 2 (OUT=64)
    int c0 = (t % CG) * 8;
    int r0 = (t / CG) * RPT;

    float acc[RPT][8];
#pragma unroll
    for (int j = 0; j < RPT; j++)
#pragma unroll
        for (int c = 0; c < 8; c++) acc[j][c] = 0.f;

#pragma unroll 4
    for (int k = 0; k < 128; k++) {
        float4 w0 = *(const float4*)(W + k * OUT + c0);
        float4 w1 = *(const float4*)(W + k * OUT + c0 + 4);
#pragma unroll
        for (int j = 0; j < RPT; j++) {
            float xv = xs[r0 + j][k];
            acc[j][0] = fmaf(xv, w0.x, acc[j][0]);
            acc[j][1] = fmaf(xv, w0.y, acc[j][1]);
            acc[j][2] = fmaf(xv, w0.z, acc[j][2]);
            acc[j][3] = fmaf(xv, w0.w, acc[j][3]);
            acc[j][4] = fmaf(xv, w1.x, acc[j][4]);
            acc[j][5] = fmaf(xv, w1.y, acc[j][5]);
            acc[j][6] = fmaf(xv, w1.z, acc[j][6]);
            acc[j][7] = fmaf(xv, w1.w, acc[j][7]);
        }
    }

#pragma unroll
    for (int j = 0; j < RPT; j++) {
        int gr = rowBase + r0 + j;
        if (gr < N) {
            float s = dinv[gr];
            float4 o0 = make_float4(acc[j][0] * s, acc[j][1] * s, acc[j][2] * s, acc[j][3] * s);
            float4 o1 = make_float4(acc[j][4] * s, acc[j][5] * s, acc[j][6] * s, acc[j][7] * s);
            float* yp = Y + (size_t)gr * OUT + c0;
            *(float4*)yp = o0;
            *(float4*)(yp + 4) = o1;
        }
    }
}

// ---------------- aggregation: wave per node, register gather-sum ----------------

template <int D, bool RELU>
__global__ __launch_bounds__(256) void agg_k(
    const float* __restrict__ H,        // [N,D] = hprime (already * dinv[src])
    const int* __restrict__ rowptr,     // [N+1]
    const int* __restrict__ col,        // [E] src per slot
    const float* __restrict__ dinv,
    const float* __restrict__ bias,     // [D]
    float* __restrict__ Y, int N) {
    int tid = threadIdx.x;
    int node = blockIdx.x * 4 + (tid >> 6);
    if (node >= N) return;
    int lane = tid & 63;
    constexpr int VF = D / 64;           // 2 (D=128) or 1 (D=64)
    const size_t fo = (size_t)lane * VF;

    float acc0, acc1 = 0.f;
    {   // self loop contribution
        const float* r = H + (size_t)node * D + fo;
        if constexpr (VF == 2) { float2 v = *(const float2*)r; acc0 = v.x; acc1 = v.y; }
        else acc0 = r[0];
    }

    int e = rowptr[node], end = rowptr[node + 1];
    for (; e + 4 <= end; e += 4) {
        int s0 = col[e], s1 = col[e + 1], s2 = col[e + 2], s3 = col[e + 3];
        const float* p0 = H + (size_t)s0 * D + fo;
        const float* p1 = H + (size_t)s1 * D + fo;
        const float* p2 = H + (size_t)s2 * D + fo;
        const float* p3 = H + (size_t)s3 * D + fo;
        if constexpr (VF == 2) {
            float2 a = *(const float2*)p0, b = *(const float2*)p1;
            float2 c = *(const float2*)p2, d = *(const float2*)p3;
            acc0 += (a.x + b.x) + (c.x + d.x);
            acc1 += (a.y + b.y) + (c.y + d.y);
        } else {
            acc0 += (p0[0] + p1[0]) + (p2[0] + p3[0]);
        }
    }
    for (; e < end; e++) {
        const float* p = H + (size_t)col[e] * D + fo;
        if constexpr (VF == 2) { float2 a = *(const float2*)p; acc0 += a.x; acc1 += a.y; }
        else acc0 += p[0];
    }

    float dv = dinv[node];
    float o0 = acc0 * dv + bias[fo];
    if (RELU) o0 = fmaxf(o0, 0.f);
    if constexpr (VF == 2) {
        float o1 = acc1 * dv + bias[fo + 1];
        if (RELU) o1 = fmaxf(o1, 0.f);
        *(float2*)(Y + (size_t)node * D + fo) = make_float2(o0, o1);
    } else {
        Y[(size_t)node * D + fo] = o0;
    }
}

// ---------------- fused actor/critic heads ----------------
// 64-node tile per 256-thread block; all intermediates in LDS.

template <int K, int OUT, int LDI, int LDO>
__device__ __forceinline__ void tile_mlp(const float (*xin)[LDI], float (*yout)[LDO],
                                         const float* __restrict__ W,
                                         const float* __restrict__ bias, int t) {
    constexpr int CG = OUT / 8;
    constexpr int RPT = (64 * CG) / 256;
    int c0 = (t % CG) * 8;
    int r0 = (t / CG) * RPT;
    float acc[RPT][8];
#pragma unroll
    for (int j = 0; j < RPT; j++)
#pragma unroll
        for (int c = 0; c < 8; c++) acc[j][c] = 0.f;
#pragma unroll 4
    for (int k = 0; k < K; k++) {
        float4 w0 = *(const float4*)(W + k * OUT + c0);
        float4 w1 = *(const float4*)(W + k * OUT + c0 + 4);
#pragma unroll
        for (int j = 0; j < RPT; j++) {
            float xv = xin[r0 + j][k];
            acc[j][0] = fmaf(xv, w0.x, acc[j][0]);
            acc[j][1] = fmaf(xv, w0.y, acc[j][1]);
            acc[j][2] = fmaf(xv, w0.z, acc[j][2]);
            acc[j][3] = fmaf(xv, w0.w, acc[j][3]);
            acc[j][4] = fmaf(xv, w1.x, acc[j][4]);
            acc[j][5] = fmaf(xv, w1.y, acc[j][5]);
            acc[j][6] = fmaf(xv, w1.z, acc[j][6]);
            acc[j][7] = fmaf(xv, w1.w, acc[j][7]);
        }
    }
#pragma unroll
    for (int j = 0; j < RPT; j++)
#pragma unroll
        for (int c = 0; c < 8; c++) {
            float v = acc[j][c] + bias[c0 + c];
            yout[r0 + j][c0 + c] = fmaxf(v, 0.f);   // all 4 hidden layers are relu
        }
}

__global__ __launch_bounds__(256) void heads_k(
    const float* __restrict__ H3,  // [N,64]
    const float* __restrict__ Wa1, const float* __restrict__ ba1,
    const float* __restrict__ Wa2, const float* __restrict__ ba2,
    const float* __restrict__ Wa3, const float* __restrict__ ba3,
    const float* __restrict__ Wc1, const float* __restrict__ bc1,
    const float* __restrict__ Wc2, const float* __restrict__ bc2,
    const float* __restrict__ Wc3, const float* __restrict__ bc3,
    float* __restrict__ out, int N) {
    constexpr int TN = 64;
    __shared__ __align__(16) float hs[TN][68];    // h3 tile (64x64)
    __shared__ float t1[TN][129];                 // 128-dim intermediate
    __shared__ float t2[TN][65];                  // 64-dim intermediate
    __shared__ float lg[TN][12];                  // probs(8) + value(1)
    int t = threadIdx.x;
    int nodeBase = blockIdx.x * TN;

    for (int i = t; i < TN * 16; i += 256) {
        int r = i >> 4, q = i & 15;
        int gn = nodeBase + r;
        float4 v = make_float4(0.f, 0.f, 0.f, 0.f);
        if (gn < N) v = ((const float4*)(H3 + (size_t)gn * 64))[q];
        *(float4*)&hs[r][q * 4] = v;
    }
    __syncthreads();

    // critic chain
    tile_mlp<64, 128, 68, 129>(hs, t1, Wc1, bc1, t);
    __syncthreads();
    tile_mlp<128, 64, 129, 65>(t1, t2, Wc2, bc2, t);
    __syncthreads();
    if (t < TN) {                                  // value head (OUT=1)
        float s = bc3[0];
        for (int k = 0; k < 64; k++) s = fmaf(t2[t][k], Wc3[k], s);
        lg[t][8] = s;
    }
    // actor chain (a1 writes t1; safe: t1 readers done at prior barrier)
    tile_mlp<64, 128, 68, 129>(hs, t1, Wa1, ba1, t);
    __syncthreads();
    tile_mlp<128, 64, 129, 65>(t1, t2, Wa2, ba2, t);
    __syncthreads();
    if (t < TN) {                                  // logits + softmax
        float l[8];
#pragma unroll
        for (int c = 0; c < 8; c++) {
            float s = ba3[c];
            for (int k = 0; k < 64; k++) s = fmaf(t2[t][k], Wa3[k * 8 + c], s);
            l[c] = s;
        }
        float m = l[0];
#pragma unroll
        for (int c = 1; c < 8; c++) m = fmaxf(m, l[c]);
        float sum = 0.f;
#pragma unroll
        for (int c = 0; c < 8; c++) { l[c] = expf(l[c] - m); sum += l[c]; }
        float inv = 1.0f / sum;
#pragma unroll
        for (int c = 0; c < 8; c++) lg[t][c] = l[c] * inv;
    }
    __syncthreads();

    // coalesced store of [64 x 9]
    for (int i = t; i < TN * 9; i += 256) {
        int r = i / 9, c = i - r * 9;
        int gn = nodeBase + r;
        if (gn < N) out[(size_t)gn * 9 + c] = lg[r][c];
    }
}

// ---------------- launch ----------------

extern "C" void kernel_launch(void* const* d_in, const int* in_sizes, int n_in,
                              void* d_out, int out_size, void* d_ws, size_t ws_size,
                              hipStream_t stream) {
    const float* x   = (const float*)d_in[0];
    const int*   ei  = (const int*)d_in[1];
    const float* W1  = (const float*)d_in[2];  const float* b1  = (const float*)d_in[3];
    const float* W2  = (const float*)d_in[4];  const float* b2  = (const float*)d_in[5];
    const float* W3  = (const float*)d_in[6];  const float* b3  = (const float*)d_in[7];
    const float* Wa1 = (const float*)d_in[8];  const float* ba1 = (const float*)d_in[9];
    const float* Wa2 = (const float*)d_in[10]; const float* ba2 = (const float*)d_in[11];
    const float* Wa3 = (const float*)d_in[12]; const float* ba3 = (const float*)d_in[13];
    const float* Wc1 = (const float*)d_in[14]; const float* bc1 = (const float*)d_in[15];
    const float* Wc2 = (const float*)d_in[16]; const float* bc2 = (const float*)d_in[17];
    const float* Wc3 = (const float*)d_in[18]; const float* bc3 = (const float*)d_in[19];
    float* out = (float*)d_out;

    const int N = in_sizes[0] / 128;     // 100000
    const int E = in_sizes[1] / 2;       // 3200000
    const int* src = ei;
    const int* dst = ei + E;

    // workspace layout
    size_t off = 0;
    auto take = [&](size_t bytes) { size_t o = off; off = WS_ALIGN(off + bytes); return o; };
    char* ws = (char*)d_ws;
    float* bufA   = (float*)(ws + take((size_t)N * 128 * 4));
    float* bufB   = (float*)(ws + take((size_t)N * 128 * 4));
    float* dinv   = (float*)(ws + take((size_t)N * 4));
    int*   cnt    = (int*)  (ws + take((size_t)N * 4));
    int*   rowptr = (int*)  (ws + take((size_t)(N + 1) * 4));
    int*   cursor = (int*)  (ws + take((size_t)N * 4));
    int*   col    = (int*)  (ws + take((size_t)E * 4));
    int*   bsum   = (int*)  (ws + take(512 * 4));
    int*   boff   = (int*)  (ws + take(512 * 4));
    (void)ws_size; (void)n_in; (void)out_size;

    const int nb  = (N + 255) / 256;     // 391 scan blocks (<512)
    const int gN  = (N + 255) / 256;
    const int gE  = (E + 255) / 256;
    const int gT  = (N + 63) / 64;       // 64-row tiles
    const int gAg = (N + 3) / 4;         // 4 nodes per block

    // degree + CSR
    zero_int_k<<<gN, 256, 0, stream>>>(cnt, N);
    count_k<<<gE, 256, 0, stream>>>(dst, cnt, E);
    dinv_k<<<gN, 256, 0, stream>>>(cnt, dinv, N);
    chunk_sum_k<<<nb, 256, 0, stream>>>(cnt, bsum, N);
    scan_mid_k<<<1, 512, 0, stream>>>(bsum, boff, nb, rowptr, N);
    scan_final_k<<<nb, 256, 0, stream>>>(cnt, boff, rowptr, cursor, N);
    fill_csr_k<<<gE, 256, 0, stream>>>(src, dst, cursor, col, E);

    // layer 1: 128 -> 128, relu
    gemm_scaled_k<128><<<gT, 256, 0, stream>>>(x, W1, dinv, bufA, N);
    agg_k<128, true><<<gAg, 256, 0, stream>>>(bufA, rowptr, col, dinv, b1, bufB, N);
    // layer 2: 128 -> 128, relu
    gemm_scaled_k<128><<<gT, 256, 0, stream>>>(bufB, W2, dinv, bufA, N);
    agg_k<128, true><<<gAg, 256, 0, stream>>>(bufA, rowptr, col, dinv, b2, bufB, N);
    // layer 3: 128 -> 64, linear
    gemm_scaled_k<64><<<gT, 256, 0, stream>>>(bufB, W3, dinv, bufA, N);
    agg_k<64, false><<<gAg, 256, 0, stream>>>(bufA, rowptr, col, dinv, b3, bufB, N);

    // heads
    heads_k<<<gT, 256, 0, stream>>>(bufB, Wa1, ba1, Wa2, ba2, Wa3, ba3,
                                    Wc1, bc1, Wc2, bc2, Wc3, bc3, out, N);
}